// Round 11
// baseline (40914.499 us; speedup 1.0000x reference)
//
#include <hip/hip_runtime.h>
#include <cstdint>

// VAN checkerboard sampler, LEVEL=0 (odd,odd positions), B=4096, L=16, H=32, K=5.
// R11: ONE batch element per 512-thread block (8 waves), two conv2 chains per
// thread -- the R7-validated arithmetic (absmax 0.0) re-shaped to escape the
// 1024-thread register wall. Evidence R0/R3/R7/R8: for 1024-thread blocks the
// allocator always plans 2-block co-residency and never grants >64 unified regs
// (R7: VGPR=64 while spilling 42GB; R8: waves_per_eu(4,4) inert). At 512 threads,
// launch_bounds(512,4) has a real 128-reg tier; s_pad pushes LDS past 160K/3 so
// LDS itself caps the CU at 2 blocks = 4 waves/SIMD = the 128-reg point -- the
// allocator has no occupancy incentive to squeeze (R4's ~550 hidden reg-shuffle
// slots/wave-step should vanish).
//
// Structure (validated bit-exact in R7/R8):
//   - each thread: ics {2*slot, 2*slot+1}; pair = accA + accB == ref's shfl merge
//   - r = pair_wl + pair_{wl+8} via one shfl_xor(32) (commuted vs ref's add-stage;
//     IEEE add commutative); 8 waves write-only to s_r -- no add stage, no mid
//     barriers (pass p-ranges disjoint)
//   - phase3: two passes reproduce the 16-virtual-wave butterfly exactly
//   - phase1 on 5/8 waves; 4 barriers/step
// All per-output fma chains keep exact (tr asc == ky asc, kx asc) order.

struct U2 { uint32_t x, y; };

// JAX Threefry-2x32 (20 rounds), matches jax/_src/prng.py
__device__ __forceinline__ U2 tf2x32(uint32_t k0, uint32_t k1, uint32_t x0, uint32_t x1) {
  uint32_t k2 = k0 ^ k1 ^ 0x1BD11BDAu;
#define TFROT(r) { x0 += x1; x1 = (x1 << (r)) | (x1 >> (32 - (r))); x1 ^= x0; }
  x0 += k0; x1 += k1;
  TFROT(13) TFROT(15) TFROT(26) TFROT(6)
  x0 += k1; x1 += k2 + 1u;
  TFROT(17) TFROT(29) TFROT(16) TFROT(24)
  x0 += k2; x1 += k0 + 2u;
  TFROT(13) TFROT(15) TFROT(26) TFROT(6)
  x0 += k0; x1 += k1 + 3u;
  TFROT(17) TFROT(29) TFROT(16) TFROT(24)
  x0 += k1; x1 += k2 + 4u;
  TFROT(13) TFROT(15) TFROT(26) TFROT(6)
  x0 += k2; x1 += k0 + 5u;
#undef TFROT
  return {x0, x1};
}

__device__ __forceinline__ float lrelu(float v) { return fmaxf(v, 0.1f * v); }

__launch_bounds__(512, 4)
__global__ void van_kernel(const float* __restrict__ gx,
                           const float* __restrict__ gw1, const float* __restrict__ gb1,
                           const float* __restrict__ gw2, const float* __restrict__ gb2,
                           const float* __restrict__ gw3, const float* __restrict__ gb3,
                           float* __restrict__ out, int B) {
  // x field with +/-6 circular halo: array row t <-> field row (t-6)&15
  __shared__ __align__(16) float s_xf[28 * 28];
  __shared__ __align__(16) float s_h1[32][9][12];   // h1 tile, row pitch 12
  __shared__ __align__(16) float s_w1[800];
  __shared__ __align__(16) float s_w3[800];
  __shared__ __align__(16) float s_r[8][800];       // r_v = pair_v + pair_{v+8}
  __shared__ float s_b1[32], s_b2[32];
  __shared__ float s_u[64];
  __shared__ float s_c3[16];
  // Occupancy limiter: total LDS > 160K/3 => at most 2 blocks/CU => 4 waves/SIMD
  // => the launch_bounds(512,4) 128-reg budget is the allocator's natural target.
  __shared__ float s_pad[1440];

  const int tid  = threadIdx.x;
  const int bg   = blockIdx.x;
  const int lane = tid & 63;
  const int wl   = tid >> 6;              // wave 0..7
  const int oc   = lane & 31;
  const int slot = wl + 8 * (lane >> 5);  // 0..15: this thread's ic-pair id
  const int icA  = 2 * slot, icB = 2 * slot + 1;

  if (B < 0) s_pad[tid] = 0.f;            // opaque fake use; never true

  // ---------------- init ----------------
  const float b3v = gb3[0];
  float w2a[25], w2b[25];
  {
    const float* pa = gw2 + (oc * 32 + icA) * 25;  // w2[oc][icA][ky][kx]
    const float* pb = gw2 + (oc * 32 + icB) * 25;
    #pragma unroll
    for (int k = 0; k < 25; ++k) { w2a[k] = pa[k]; w2b[k] = pb[k]; }
  }
  for (int t = tid; t < 800; t += 512) { s_w1[t] = gw1[t]; s_w3[t] = gw3[t]; }
  if (tid < 32) { s_b1[tid] = gb1[tid]; s_b2[tid] = gb2[tid]; }
  for (int t = tid; t < 784; t += 512) {
    int rr = t / 28, cc = t - rr * 28;
    int fy = (rr - 6) & 15, fx = (cc - 6) & 15;
    s_xf[t] = gx[bg * 256 + fy * 16 + fx];
  }
  if (tid < 64) {
    // jax_threefry_partitionable=True: key_s = tf(root=(0,42),(0,s)); bits = x^y of tf(key_s,(0,b))
    U2 key = tf2x32(0u, 42u, 0u, (uint32_t)tid);
    U2 tt  = tf2x32(key.x, key.y, 0u, (uint32_t)bg);
    uint32_t bits = tt.x ^ tt.y;
    s_u[tid] = __uint_as_float(0x3F800000u | (bits >> 9)) - 1.0f;
  }
  float logq = 0.f;   // only thread 0's copy is meaningful
  __syncthreads();

  #pragma unroll 1
  for (int s = 0; s < 64; ++s) {
    const int i = 2 * (s >> 3) + 1;
    const int j = 2 * (s & 7) + 1;

    // ---- phase 1: h1 tile (9x9x32); tile (r,c) <-> field (i-4+r, j-4+c) ----
    if (tid < 288) {
      const int t_ic = tid / 9;
      const int r    = tid - t_ic * 9;
      const float bb = s_b1[t_ic];
      float a[9];
      #pragma unroll
      for (int c = 0; c < 9; ++c) a[c] = bb;
      #pragma unroll
      for (int ky = 0; ky < 5; ++ky) {
        const float* xr = &s_xf[(i + r + ky) * 28 + j];
        float xv[13];
        #pragma unroll
        for (int m = 0; m < 13; ++m) xv[m] = xr[m];
        #pragma unroll
        for (int kx = 0; kx < 5; ++kx) {
          const float w = s_w1[t_ic * 25 + ky * 5 + kx];
          #pragma unroll
          for (int c = 0; c < 9; ++c) a[c] = fmaf(xv[c + kx], w, a[c]);
        }
      }
      #pragma unroll
      for (int c = 0; c < 9; ++c) s_h1[t_ic][r][c] = lrelu(a[c]);
    }
    __syncthreads();

    // ---- phase 2: conv2, two chains per thread, 2 position passes ----
    // Each chain's per-output fma order: (tr asc == ky asc, kx asc) -- identical
    // to reference. pair = accA + accB (even ic first, as the old shfl merge).
    // r = pair + shfl_xor(pair,32): lane<32 holds pair_wl + pair_{wl+8}
    // (reference computed pair_{wl+8} + pair_wl; IEEE add commutative => same bits).
#define CHAIN_PASS(HP, W, ACC, DYLO, DYHI, TRLO, TRHI, NACC)                       \
    {                                                                              \
      _Pragma("unroll")                                                            \
      for (int p = 0; p < (NACC); ++p) (ACC)[p] = 0.f;                             \
      _Pragma("unroll")                                                            \
      for (int tr = (TRLO); tr <= (TRHI); ++tr) {                                  \
        const float4* rp = (const float4*)(&(HP)[tr][0]);                          \
        const float4 ra = rp[0], rb = rp[1];                                       \
        const float r8 = (HP)[tr][8];                                              \
        const float row[9] = {ra.x, ra.y, ra.z, ra.w, rb.x, rb.y, rb.z, rb.w, r8}; \
        _Pragma("unroll")                                                          \
        for (int dy = (DYLO); dy <= (DYHI); ++dy) {                                \
          const int ky = tr - dy;                                                  \
          if (ky < 0 || ky > 4) continue;   /* folds at compile time */            \
          _Pragma("unroll")                                                        \
          for (int kx = 0; kx < 5; ++kx) {                                         \
            const float w = (W)[ky * 5 + kx];                                      \
            _Pragma("unroll")                                                      \
            for (int dx = 0; dx < 5; ++dx)                                         \
              (ACC)[(dy - (DYLO)) * 5 + dx] = fmaf(row[dx + kx], w,                \
                                                   (ACC)[(dy - (DYLO)) * 5 + dx]); \
          }                                                                        \
        }                                                                          \
      }                                                                            \
    }

    const float (*hpA)[12] = s_h1[icA];
    const float (*hpB)[12] = s_h1[icB];

    {   // pass A: dy {0,1,2}, p = 0..14, rows tr 0..6
      float accA[15], accB[15];
      CHAIN_PASS(hpA, w2a, accA, 0, 2, 0, 6, 15)
      CHAIN_PASS(hpB, w2b, accB, 0, 2, 0, 6, 15)
      #pragma unroll
      for (int p = 0; p < 15; ++p) {
        float pair = accA[p] + accB[p];
        float r = pair + __shfl_xor(pair, 32, 64);
        if (lane < 32) s_r[wl][p * 32 + oc] = r;
      }
    }
    {   // pass B: dy {3,4}, p = 15..24, rows tr 3..8
      float accA[10], accB[10];
      CHAIN_PASS(hpA, w2a, accA, 3, 4, 3, 8, 10)
      CHAIN_PASS(hpB, w2b, accB, 3, 4, 3, 8, 10)
      #pragma unroll
      for (int p = 0; p < 10; ++p) {
        float pair = accA[p] + accB[p];
        float r = pair + __shfl_xor(pair, 32, 64);
        if (lane < 32) s_r[wl][(p + 15) * 32 + oc] = r;
      }
    }
#undef CHAIN_PASS
    __syncthreads();

    // ---- phase 3: a2 sum (fixed order), lrelu, conv3 partials ----
    // Two passes reproduce the original 16-virtual-wave butterfly exactly:
    // pass 0 -> virtual tids 0..511 (c3[0..7]), pass 1 -> 512..1023 (c3[8..15]).
    #pragma unroll
    for (int pass = 0; pass < 2; ++pass) {
      const int vt = tid + 512 * pass;
      float v3 = 0.f;
      if (vt < 800) {
        float t = 0.f;
        #pragma unroll
        for (int v = 0; v < 8; ++v) t += s_r[v][vt];
        t += s_b2[vt & 31];
        const float h2 = lrelu(t);
        v3 = h2 * s_w3[(vt & 31) * 25 + (vt >> 5)];   // w3[oc][pos]
      }
      #pragma unroll
      for (int m = 32; m >= 1; m >>= 1) v3 += __shfl_xor(v3, m, 64);
      if (lane == 0) s_c3[wl + 8 * pass] = v3;
    }
    __syncthreads();

    // ---- phase 4: sample (thread 0), update x field halo copies ----
    if (tid == 0) {
      float logit = b3v;
      #pragma unroll
      for (int v = 0; v < 16; ++v) logit += s_c3[v];
      const float pr   = 1.f / (1.f + expf(-logit));
      const float u    = s_u[s];
      const float samp = (u < pr) ? 1.f : -1.f;
      const int r1 = i + 6, c1 = j + 6;
      const int r2 = (i < 6) ? i + 22 : ((i >= 10) ? i - 10 : r1);
      const int c2 = (j < 6) ? j + 22 : ((j >= 10) ? j - 10 : c1);
      s_xf[r1 * 28 + c1] = samp; s_xf[r1 * 28 + c2] = samp;
      s_xf[r2 * 28 + c1] = samp; s_xf[r2 * 28 + c2] = samp;
      logq += (samp > 0.f) ? logf(pr + 1e-7f) : logf(1.f - pr + 1e-7f);
    }
    __syncthreads();
  }

  // ---------------- output ----------------
  if (tid < 256)
    out[bg * 256 + tid] = s_xf[((tid >> 4) + 6) * 28 + (tid & 15) + 6];
  if (tid == 0)
    out[B * 256 + bg] = logq;
}

extern "C" void kernel_launch(void* const* d_in, const int* in_sizes, int n_in,
                              void* d_out, int out_size, void* d_ws, size_t ws_size,
                              hipStream_t stream) {
  const float* gx  = (const float*)d_in[0];
  const float* gw1 = (const float*)d_in[1];
  const float* gb1 = (const float*)d_in[2];
  const float* gw2 = (const float*)d_in[3];
  const float* gb2 = (const float*)d_in[4];
  const float* gw3 = (const float*)d_in[5];
  const float* gb3 = (const float*)d_in[6];
  float* out = (float*)d_out;
  const int B = in_sizes[0] / 256;

  hipLaunchKernelGGL(van_kernel, dim3(B), dim3(512), 0, stream,
                     gx, gw1, gb1, gw2, gb2, gw3, gb3, out, B);
}

// Round 12
// 6360.151 us; speedup vs baseline: 6.4329x; 6.4329x over previous
//
#include <hip/hip_runtime.h>
#include <cstdint>

// VAN checkerboard sampler, LEVEL=0 (odd,odd positions), B=4096, L=16, H=32, K=5.
// One 1024-thread block per batch element; all 64 autoregressive steps in-kernel.
// Deterministic reductions only (graph replay must revalidate bit-identically).
//
// R12 = R4 (2-pass conv2, best at 4996us, bit-exact) with w2 weights moved from
// per-thread registers to LDS. Rationale: R7/R8/R11 proved the toolchain never
// grants >64 unified regs/wave here; 25 per-thread weights + 15 accs + row 9
// cannot fit 32 arch regs, so weights lived in AGPRs with hidden compiler traffic
// inside the 625-FMA hot loop (measured ~2900 VALU-busy cyc/wave-step vs ~1530
// countable). Moving weights to LDS empties the AGPR involvement: arch live =
// acc[15] + row[9] + addr ~ 28, fits the 32-reg file cleanly.
//  - s_w2t layout [k][ic*32+oc]: 64 lanes (oc 0..31 x ic pair) hit banks 0..31
//    twice = 2-way broadcast, conflict-free. 125 ds_read_b32/thread-step, each
//    reused for 5 FMAs (1:5), latency hideable. Same fp32 value => bit-exact.
//  - LDS ~148KB -> 1 block/CU (sacrifices R3's 2-block overlap for loop speed).
// All per-output fma chains keep exact (tr asc == ky asc, kx asc) order; merge
// tree and phase-3 sum orders unchanged from R4.

struct U2 { uint32_t x, y; };

// JAX Threefry-2x32 (20 rounds), matches jax/_src/prng.py
__device__ __forceinline__ U2 tf2x32(uint32_t k0, uint32_t k1, uint32_t x0, uint32_t x1) {
  uint32_t k2 = k0 ^ k1 ^ 0x1BD11BDAu;
#define TFROT(r) { x0 += x1; x1 = (x1 << (r)) | (x1 >> (32 - (r))); x1 ^= x0; }
  x0 += k0; x1 += k1;
  TFROT(13) TFROT(15) TFROT(26) TFROT(6)
  x0 += k1; x1 += k2 + 1u;
  TFROT(17) TFROT(29) TFROT(16) TFROT(24)
  x0 += k2; x1 += k0 + 2u;
  TFROT(13) TFROT(15) TFROT(26) TFROT(6)
  x0 += k0; x1 += k1 + 3u;
  TFROT(17) TFROT(29) TFROT(16) TFROT(24)
  x0 += k1; x1 += k2 + 4u;
  TFROT(13) TFROT(15) TFROT(26) TFROT(6)
  x0 += k2; x1 += k0 + 5u;
#undef TFROT
  return {x0, x1};
}

__device__ __forceinline__ float lrelu(float v) { return fmaxf(v, 0.1f * v); }

__launch_bounds__(1024, 4)
__global__ void van_kernel(const float* __restrict__ gx,
                           const float* __restrict__ gw1, const float* __restrict__ gb1,
                           const float* __restrict__ gw2, const float* __restrict__ gb2,
                           const float* __restrict__ gw3, const float* __restrict__ gb3,
                           float* __restrict__ out, int B) {
  // x field with +/-6 circular halo: array row t <-> field row (t-6)&15
  __shared__ __align__(16) float s_xf[28 * 28];
  __shared__ __align__(16) float s_h1[32][9][12];   // h1 tile, row pitch 12 (16B aligned rows)
  __shared__ __align__(16) float s_w1[800];
  __shared__ __align__(16) float s_w3[800];
  __shared__ __align__(16) float s_buf[8][800];     // reduction tree buffers
  __shared__ __align__(16) float s_w2t[25 * 1024];  // [k][ic*32+oc], conflict-free
  __shared__ float s_b1[32], s_b2[32];
  __shared__ float s_u[64];                          // per-step uniforms for this batch elem
  __shared__ float s_c3[16];                         // per-wave conv3 partials

  const int tid  = threadIdx.x;
  const int bg   = blockIdx.x;
  const int lane = tid & 63;
  const int wv   = tid >> 6;
  const int oc   = tid & 31;   // conv2 out-channel of this thread
  const int ic   = tid >> 5;   // conv2 in-channel of this thread

  // ---------------- init ----------------
  const float b3v = gb3[0];
  // transposed w2 fill: s_w2t[k*1024 + ic*32 + oc] = w2[oc][ic][k]  (once, tiny)
  for (int idx = tid; idx < 25 * 1024; idx += 1024) {
    const int k    = idx >> 10;
    const int rem  = idx & 1023;
    const int t_ic = rem >> 5;
    const int t_oc = rem & 31;
    s_w2t[idx] = gw2[(t_oc * 32 + t_ic) * 25 + k];
  }
  if (tid < 800) { s_w1[tid] = gw1[tid]; s_w3[tid] = gw3[tid]; }
  if (tid < 32)  { s_b1[tid] = gb1[tid]; s_b2[tid] = gb2[tid]; }
  if (tid < 784) {
    int rr = tid / 28, cc = tid - rr * 28;
    int fy = (rr - 6) & 15, fx = (cc - 6) & 15;
    s_xf[tid] = gx[bg * 256 + fy * 16 + fx];
  }
  if (tid < 64) {
    // jax_threefry_partitionable=True conventions:
    // key_s = threefry(root=(0,42), (0, s)); bits(b) = x^y of threefry(key_s, (0, b))
    U2 key = tf2x32(0u, 42u, 0u, (uint32_t)tid);
    U2 tt  = tf2x32(key.x, key.y, 0u, (uint32_t)bg);
    uint32_t bits = tt.x ^ tt.y;
    s_u[tid] = __uint_as_float(0x3F800000u | (bits >> 9)) - 1.0f;
  }
  float logq = 0.f;   // only thread 0's copy is meaningful
  const float* wp = &s_w2t[ic * 32 + oc];   // this thread's weight column
  __syncthreads();

  #pragma unroll 1
  for (int s = 0; s < 64; ++s) {
    const int i = 2 * (s >> 3) + 1;
    const int j = 2 * (s & 7) + 1;

    // ---- phase 1: h1 tile (9x9x32) from x; tile (r,c) <-> field (i-4+r, j-4+c) ----
    if (tid < 288) {
      const int t_ic = tid / 9;
      const int r    = tid - t_ic * 9;
      const float bb = s_b1[t_ic];
      float a[9];
      #pragma unroll
      for (int c = 0; c < 9; ++c) a[c] = bb;
      #pragma unroll
      for (int ky = 0; ky < 5; ++ky) {
        const float* xr = &s_xf[(i + r + ky) * 28 + j];   // field row i-6+r+ky, cols j-6..j+6
        float xv[13];
        #pragma unroll
        for (int m = 0; m < 13; ++m) xv[m] = xr[m];
        #pragma unroll
        for (int kx = 0; kx < 5; ++kx) {
          const float w = s_w1[t_ic * 25 + ky * 5 + kx];
          #pragma unroll
          for (int c = 0; c < 9; ++c) a[c] = fmaf(xv[c + kx], w, a[c]);
        }
      }
      #pragma unroll
      for (int c = 0; c < 9; ++c) s_h1[t_ic][r][c] = lrelu(a[c]);
    }
    __syncthreads();

    // ---- phase 2: conv2 at 25 positions, 2 passes (15/10 accs) ----
    // Weight for each unrolled (ky,kx) site: one ds_read_b32 from s_w2t (2-way
    // broadcast, conflict-free), reused across the 5 dx FMAs. Same value as the
    // old register copy => bit-identical chains.
#define CONV2_PASS(DYLO, DYHI, TRLO, TRHI, NACC)                                   \
    {                                                                              \
      float acc[NACC];                                                             \
      _Pragma("unroll")                                                            \
      for (int p = 0; p < (NACC); ++p) acc[p] = 0.f;                               \
      _Pragma("unroll")                                                            \
      for (int tr = (TRLO); tr <= (TRHI); ++tr) {                                  \
        const float4* rp = (const float4*)(&s_h1[ic][tr][0]);                      \
        const float4 ra = rp[0], rb = rp[1];                                       \
        const float r8 = s_h1[ic][tr][8];                                          \
        const float row[9] = {ra.x, ra.y, ra.z, ra.w, rb.x, rb.y, rb.z, rb.w, r8}; \
        _Pragma("unroll")                                                          \
        for (int dy = (DYLO); dy <= (DYHI); ++dy) {                                \
          const int ky = tr - dy;                                                  \
          if (ky < 0 || ky > 4) continue;   /* folds at compile time */            \
          _Pragma("unroll")                                                        \
          for (int kx = 0; kx < 5; ++kx) {                                         \
            const float w = wp[(ky * 5 + kx) * 1024];                              \
            _Pragma("unroll")                                                      \
            for (int dx = 0; dx < 5; ++dx)                                         \
              acc[(dy - (DYLO)) * 5 + dx] = fmaf(row[dx + kx], w,                  \
                                                 acc[(dy - (DYLO)) * 5 + dx]);     \
          }                                                                        \
        }                                                                          \
      }                                                                            \
      _Pragma("unroll")                                                            \
      for (int p = 0; p < (NACC); ++p) acc[p] += __shfl_xor(acc[p], 32, 64);       \
      if (wv >= 8 && lane < 32) {                                                  \
        _Pragma("unroll")                                                          \
        for (int p = 0; p < (NACC); ++p)                                           \
          s_buf[wv - 8][((DYLO) * 5 + p) * 32 + lane] = acc[p];                    \
      }                                                                            \
      __syncthreads();                                                             \
      if (wv < 8 && lane < 32) {                                                   \
        _Pragma("unroll")                                                          \
        for (int p = 0; p < (NACC); ++p)                                           \
          s_buf[wv][((DYLO) * 5 + p) * 32 + lane] += acc[p];                       \
      }                                                                            \
    }

    CONV2_PASS(0, 2, 0, 6, 15)   // p = 0..14,  rows 0..6
    CONV2_PASS(3, 4, 3, 8, 10)   // p = 15..24, rows 3..8
#undef CONV2_PASS
    __syncthreads();

    // ---- phase 3: final a2 sum (fixed order), lrelu, conv3 partials ----
    float v3 = 0.f;
    if (tid < 800) {
      float t = 0.f;
      #pragma unroll
      for (int v = 0; v < 8; ++v) t += s_buf[v][tid];
      t += s_b2[tid & 31];
      const float h2 = lrelu(t);
      v3 = h2 * s_w3[(tid & 31) * 25 + (tid >> 5)];   // w3[oc][pos]
    }
    #pragma unroll
    for (int m = 32; m >= 1; m >>= 1) v3 += __shfl_xor(v3, m, 64);
    if (lane == 0) s_c3[wv] = v3;
    __syncthreads();

    // ---- phase 4: sample (thread 0), update x field halo copies ----
    if (tid == 0) {
      float logit = b3v;
      #pragma unroll
      for (int v = 0; v < 16; ++v) logit += s_c3[v];
      const float pr   = 1.f / (1.f + expf(-logit));
      const float u    = s_u[s];
      const float samp = (u < pr) ? 1.f : -1.f;
      const int r1 = i + 6, c1 = j + 6;
      const int r2 = (i < 6) ? i + 22 : ((i >= 10) ? i - 10 : r1);
      const int c2 = (j < 6) ? j + 22 : ((j >= 10) ? j - 10 : c1);
      s_xf[r1 * 28 + c1] = samp; s_xf[r1 * 28 + c2] = samp;
      s_xf[r2 * 28 + c1] = samp; s_xf[r2 * 28 + c2] = samp;
      logq += (samp > 0.f) ? logf(pr + 1e-7f) : logf(1.f - pr + 1e-7f);
    }
    __syncthreads();
  }

  // ---------------- output ----------------
  if (tid < 256)
    out[bg * 256 + tid] = s_xf[((tid >> 4) + 6) * 28 + (tid & 15) + 6];
  if (tid == 0)
    out[B * 256 + bg] = logq;
}

extern "C" void kernel_launch(void* const* d_in, const int* in_sizes, int n_in,
                              void* d_out, int out_size, void* d_ws, size_t ws_size,
                              hipStream_t stream) {
  const float* gx  = (const float*)d_in[0];
  const float* gw1 = (const float*)d_in[1];
  const float* gb1 = (const float*)d_in[2];
  const float* gw2 = (const float*)d_in[3];
  const float* gb2 = (const float*)d_in[4];
  const float* gw3 = (const float*)d_in[5];
  const float* gb3 = (const float*)d_in[6];
  float* out = (float*)d_out;
  const int B = in_sizes[0] / 256;

  hipLaunchKernelGGL(van_kernel, dim3(B), dim3(1024), 0, stream,
                     gx, gw1, gb1, gw2, gb2, gw3, gb3, out, B);
}